// Round 13
// baseline (74.283 us; speedup 1.0000x reference)
//
#include <hip/hip_runtime.h>
#include <math.h>

// CircleLoss, symmetric-triangle bf16-MFMA, LDS-free fragment loads.
//   R12 lesson: __launch_bounds__(256,4) = 4 waves/EU -> VGPR cap 128, compiler
//   picked 64 and SPILLED the 64-VGPR accumulator to scratch (WRITE_SIZE 37MB,
//   +10us). R13: (256,2) -> cap 256, compiler fits (~128 VGPR, R11 evidence),
//   no spill; occupancy still ~4 blocks/CU by VGPR curve (no LDS, 128 VGPR).
//   Structure: fragments direct from global (featsN L2-resident; MFMA fragments
//   are contiguous 16B row slices), no barriers. u-form epilogue + DIRECT (P,N)
//   accumulation; transposed partial[slot][row] packed bf16. Triangle: tile
//   pairs (RT<=CT); slots {2CT+wc} ∪ {2RT+wr} cover 0..127 once per row.
// ws: 2MB featsN + 4MB partial + 256B blocksum = 6.2MB.

#define DIM 128
typedef short bf16x8 __attribute__((ext_vector_type(8)));
typedef float f32x4 __attribute__((ext_vector_type(4)));

#if __has_builtin(__builtin_amdgcn_exp2f)
#define EXP2F __builtin_amdgcn_exp2f
#else
#define EXP2F exp2f
#endif

__device__ __forceinline__ unsigned short f2bf(float f) {
    unsigned int b = __float_as_uint(f);
    unsigned int r = (b + 0x7FFFu + ((b >> 16) & 1u)) >> 16;   // RN-even
    return (unsigned short)r;
}
__device__ __forceinline__ unsigned int packPN(float p, float n) {
    return (unsigned int)f2bf(p) | ((unsigned int)f2bf(n) << 16);
}

// ---------------- Kernel 1: normalize + quantize ----------------
__global__ void prep_kernel(const float* __restrict__ feats,
                            unsigned int* __restrict__ featsN, int B) {
    int wave = (blockIdx.x * blockDim.x + threadIdx.x) >> 6;
    int lane = threadIdx.x & 63;
    if (wave >= B) return;
    const float2* rp = (const float2*)(feats + (size_t)wave * DIM);
    float2 v = rp[lane];
    float s = v.x * v.x + v.y * v.y;
#pragma unroll
    for (int off = 32; off; off >>= 1) s += __shfl_xor(s, off);
    float inv = rsqrtf(s);
    featsN[(size_t)wave * 64 + lane] =
        (unsigned int)f2bf(v.x * inv) | ((unsigned int)f2bf(v.y * inv) << 16);
}

// ---------------- Kernel 2: triangular fused MFMA + masked exp ----------------
// 2080 blocks = tile pairs (RT,CT), RT<=CT. 4 waves in 2x2 of 64x64. No LDS.
__global__ __launch_bounds__(256, 2) void circle_main_kernel(
    const unsigned short* __restrict__ featsN, const int* __restrict__ labels,
    unsigned int* __restrict__ partial, int B) {
    // ---- unrank bid -> (RT, CT), RT <= CT ----
    int bid = blockIdx.x;
    int RT = (int)((129.0 - sqrt(16641.0 - 8.0 * (double)bid)) * 0.5);
    RT = RT < 0 ? 0 : (RT > 63 ? 63 : RT);
    while (64 * RT - (RT * (RT - 1)) / 2 > bid) --RT;
    while (64 * (RT + 1) - ((RT + 1) * RT) / 2 <= bid) ++RT;
    const int CT = RT + (bid - (64 * RT - (RT * (RT - 1)) / 2));
    const bool diag = (RT == CT);

    const int tid = threadIdx.x;
    const int lane = tid & 63;
    const int wv = tid >> 6;
    const int wr = wv >> 1, wc = wv & 1;
    const int lg = lane >> 4;
    const int l15 = lane & 15;

    // ---- MFMA: fragments loaded directly from global (L2-resident) ----
    f32x4 acc[4][4];
#pragma unroll
    for (int m = 0; m < 4; ++m)
#pragma unroll
        for (int n = 0; n < 4; ++n) acc[m][n] = (f32x4){0.f, 0.f, 0.f, 0.f};
#pragma unroll
    for (int kk = 0; kk < 4; ++kk) {
        bf16x8 af[4], bfr[4];
#pragma unroll
        for (int m = 0; m < 4; ++m) {
            int row = RT * 128 + wr * 64 + m * 16 + l15;
            af[m] = __builtin_bit_cast(bf16x8,
                *(const int4*)(featsN + (size_t)row * DIM + (kk * 4 + lg) * 8));
        }
#pragma unroll
        for (int n = 0; n < 4; ++n) {
            int row = CT * 128 + wc * 64 + n * 16 + l15;
            bfr[n] = __builtin_bit_cast(bf16x8,
                *(const int4*)(featsN + (size_t)row * DIM + (kk * 4 + lg) * 8));
        }
#pragma unroll
        for (int m = 0; m < 4; ++m)
#pragma unroll
            for (int n = 0; n < 4; ++n)
                acc[m][n] = __builtin_amdgcn_mfma_f32_16x16x32_bf16(
                    af[m], bfr[n], acc[m][n], 0, 0, 0);
    }

    // ---- epilogue: u-form, DIRECT (P, N) accumulation ----
    const int rowbase = RT * 128 + wr * 64;
    const int colbase = CT * 128 + wc * 64;
    const float S2 = 46.166241308446828f;   // 32*log2(e)
    const float C2 = -23.083120654223414f;  // -0.5*S2

    int lc[4], lr[4][4];
#pragma unroll
    for (int n = 0; n < 4; ++n) lc[n] = labels[colbase + n * 16 + l15];
#pragma unroll
    for (int m = 0; m < 4; ++m)
#pragma unroll
        for (int r = 0; r < 4; ++r) lr[m][r] = labels[rowbase + m * 16 + lg * 4 + r];

    float rN[4][4], rP[4][4];
    float cN[4] = {0.f, 0.f, 0.f, 0.f}, cP[4] = {0.f, 0.f, 0.f, 0.f};

    if (diag) {
#pragma unroll
        for (int m = 0; m < 4; ++m) {
#pragma unroll
            for (int r = 0; r < 4; ++r) {
                const int grow = rowbase + m * 16 + lg * 4 + r;
                const int lrow = lr[m][r];
                float psum = 0.f, nsum = 0.f;
#pragma unroll
                for (int n = 0; n < 4; ++n) {
                    float sim = acc[m][n][r];
                    bool same = (lrow == lc[n]);
                    float u = same ? (1.25f - sim) : (sim + 0.25f);
                    float e2 = fmaxf(u, 0.f) * fmaf(S2, u, C2);
                    float v = EXP2F(e2);
                    bool self = (grow == colbase + n * 16 + l15);
                    float pv = (same && !self) ? v : 0.f;
                    float nv = same ? 0.f : v;   // self is same -> excluded
                    psum += pv; nsum += nv;
                }
                rP[m][r] = psum; rN[m][r] = nsum;
            }
        }
    } else {
#pragma unroll
        for (int m = 0; m < 4; ++m) {
#pragma unroll
            for (int r = 0; r < 4; ++r) {
                const int lrow = lr[m][r];
                float psum = 0.f, nsum = 0.f;
#pragma unroll
                for (int n = 0; n < 4; ++n) {
                    float sim = acc[m][n][r];
                    bool same = (lrow == lc[n]);
                    float u = same ? (1.25f - sim) : (sim + 0.25f);
                    float e2 = fmaxf(u, 0.f) * fmaf(S2, u, C2);
                    float v = EXP2F(e2);
                    float pv = same ? v : 0.f;
                    float nv = v - pv;            // exact: pv is v or 0
                    psum += pv; nsum += nv;
                    cP[n] += pv; cN[n] += nv;
                }
                rP[m][r] = psum; rN[m][r] = nsum;
            }
        }
    }

    // ---- row partials: butterfly over l15, slot = CT*2 + wc (transposed) ----
#pragma unroll
    for (int m = 0; m < 4; ++m) {
#pragma unroll
        for (int r = 0; r < 4; ++r) {
            float p = rP[m][r], n_ = rN[m][r];
#pragma unroll
            for (int off = 1; off < 16; off <<= 1) {
                p += __shfl_xor(p, off);
                n_ += __shfl_xor(n_, off);
            }
            if (l15 == 0) {
                int grow = rowbase + m * 16 + lg * 4 + r;
                partial[(size_t)(CT * 2 + wc) * B + grow] = packPN(p, n_);
            }
        }
    }
    // ---- col partials (off-diag only): reduce over lane groups, slot = RT*2 + wr ----
    if (!diag) {
#pragma unroll
        for (int n = 0; n < 4; ++n) {
            float p = cP[n], n_ = cN[n];
            p += __shfl_xor(p, 16); p += __shfl_xor(p, 32);
            n_ += __shfl_xor(n_, 16); n_ += __shfl_xor(n_, 32);
            if (lg == 0) {
                int gcol = colbase + n * 16 + l15;
                partial[(size_t)(RT * 2 + wr) * B + gcol] = packPN(p, n_);
            }
        }
    }
}

// ---------------- Kernel 3: per-row log1p(p*n), block sums ----------------
__global__ void rowloss_kernel(const unsigned int* __restrict__ partial,
                               double* __restrict__ blocksum, int B) {
    __shared__ double sdata[256];
    int tid = threadIdx.x;
    int row = blockIdx.x * 256 + tid;
    float p = 0.f, n = 0.f;
#pragma unroll
    for (int c = 0; c < 128; ++c) {
        unsigned int v = partial[(size_t)c * B + row];
        p += __uint_as_float(v << 16);
        n += __uint_as_float(v & 0xFFFF0000u);
    }
    sdata[tid] = log1p((double)p * (double)n);
    __syncthreads();
    for (int s = 128; s; s >>= 1) {
        if (tid < s) sdata[tid] += sdata[tid + s];
        __syncthreads();
    }
    if (tid == 0) blocksum[blockIdx.x] = sdata[0];
}

__global__ void final_kernel(const double* __restrict__ blocksum,
                             float* __restrict__ out, int nblk, int B) {
    __shared__ double sdata[64];
    int tid = threadIdx.x;
    sdata[tid] = (tid < nblk) ? blocksum[tid] : 0.0;
    __syncthreads();
    for (int s = 32; s; s >>= 1) {
        if (tid < s) sdata[tid] += sdata[tid + s];
        __syncthreads();
    }
    if (tid == 0) out[0] = (float)(sdata[0] / (double)B);
}

extern "C" void kernel_launch(void* const* d_in, const int* in_sizes, int n_in,
                              void* d_out, int out_size, void* d_ws, size_t ws_size,
                              hipStream_t stream) {
    const float* feats = (const float*)d_in[0];
    const int* labels = (const int*)d_in[1];
    float* out = (float*)d_out;
    int B = in_sizes[1];  // 8192

    // ws: featsN bf16 [B][128] (2MB) | partial u32 [128][B] (4MB) | blocksum (256B)
    unsigned int* featsN = (unsigned int*)d_ws;
    size_t off1 = ((size_t)B * DIM * 2 + 255) & ~(size_t)255;
    unsigned int* partial = (unsigned int*)((char*)d_ws + off1);
    size_t off2 = off1 + (((size_t)B * 128 * sizeof(unsigned int) + 255) & ~(size_t)255);
    double* blocksum = (double*)((char*)d_ws + off2);

    prep_kernel<<<B / 4, 256, 0, stream>>>(feats, featsN, B);

    int ntiles = B / 128;                      // 64
    int nblocks = ntiles * (ntiles + 1) / 2;   // 2080
    circle_main_kernel<<<nblocks, 256, 0, stream>>>((const unsigned short*)featsN,
                                                    labels, partial, B);

    int nblk = B / 256;                        // 32
    rowloss_kernel<<<nblk, 256, 0, stream>>>(partial, blocksum, B);
    final_kernel<<<1, 64, 0, stream>>>(blocksum, out, nblk, B);
}

// Round 14
// 44.001 us; speedup vs baseline: 1.6882x; 1.6882x over previous
//
#include <hip/hip_runtime.h>
#include <math.h>

// CircleLoss, symmetric-triangle bf16-MFMA (R11 base) + LDS-transpose reduction.
//   R13 lesson: no-LDS fragment loads regress (latency interleaved with MFMA);
//   R11's LDS staging stays. NEW R14 finding: the butterfly reduction was
//   ~288 ds_swizzle ops/wave = the dominant DS-pipe load (~30us/CU). Replaced
//   with an LDS transpose: wave writes [64][17] float2 (aliased over dead A/B
//   tiles, barriers both sides), lane L reads row L contiguously -> 32 DS ops
//   and a fully-coalesced 64-lane global write.
//   Numerics: u-form epilogue + DIRECT (P,N) accumulation (no T-P cancellation);
//   transposed partial[slot][row] packed bf16. Triangle: tile pairs (RT<=CT);
//   slots {2CT+wc} ∪ {2RT+wr} cover 0..127 once per row. No atomics.
// ws: 2MB featsN + 4MB partial + 256B blocksum = 6.2MB.

#define DIM 128
typedef short bf16x8 __attribute__((ext_vector_type(8)));
typedef float f32x4 __attribute__((ext_vector_type(4)));

#if __has_builtin(__builtin_amdgcn_exp2f)
#define EXP2F __builtin_amdgcn_exp2f
#else
#define EXP2F exp2f
#endif

__device__ __forceinline__ unsigned short f2bf(float f) {
    unsigned int b = __float_as_uint(f);
    unsigned int r = (b + 0x7FFFu + ((b >> 16) & 1u)) >> 16;   // RN-even
    return (unsigned short)r;
}
__device__ __forceinline__ unsigned int packPN(float p, float n) {
    return (unsigned int)f2bf(p) | ((unsigned int)f2bf(n) << 16);
}

// ---------------- Kernel 1: normalize + quantize ----------------
__global__ void prep_kernel(const float* __restrict__ feats,
                            unsigned int* __restrict__ featsN, int B) {
    int wave = (blockIdx.x * blockDim.x + threadIdx.x) >> 6;
    int lane = threadIdx.x & 63;
    if (wave >= B) return;
    const float2* rp = (const float2*)(feats + (size_t)wave * DIM);
    float2 v = rp[lane];
    float s = v.x * v.x + v.y * v.y;
#pragma unroll
    for (int off = 32; off; off >>= 1) s += __shfl_xor(s, off);
    float inv = rsqrtf(s);
    featsN[(size_t)wave * 64 + lane] =
        (unsigned int)f2bf(v.x * inv) | ((unsigned int)f2bf(v.y * inv) << 16);
}

// ---------------- Kernel 2: triangular fused MFMA + masked exp ----------------
// 2080 blocks = tile pairs (RT,CT), RT<=CT. 4 waves in 2x2 of 64x64.
__global__ __launch_bounds__(256, 2) void circle_main_kernel(
    const unsigned short* __restrict__ featsN, const int* __restrict__ labels,
    unsigned int* __restrict__ partial, int B) {
    __shared__ unsigned char smem[65536] __attribute__((aligned(16)));
    unsigned char* Al = smem;
    unsigned char* Bl = smem + 32768;
    // transpose scratch aliases the (dead-after-MFMA) tiles: 4*64*17*8B = 34816B
    float2* tbuf = (float2*)smem;

    // ---- unrank bid -> (RT, CT), RT <= CT ----
    int bid = blockIdx.x;
    int RT = (int)((129.0 - sqrt(16641.0 - 8.0 * (double)bid)) * 0.5);
    RT = RT < 0 ? 0 : (RT > 63 ? 63 : RT);
    while (64 * RT - (RT * (RT - 1)) / 2 > bid) --RT;
    while (64 * (RT + 1) - ((RT + 1) * RT) / 2 <= bid) ++RT;
    const int CT = RT + (bid - (64 * RT - (RT * (RT - 1)) / 2));
    const bool diag = (RT == CT);

    const int tid = threadIdx.x;
    const int lane = tid & 63;
    const int wv = tid >> 6;
    const int wr = wv >> 1, wc = wv & 1;
    const int lg = lane >> 4;
    const int l15 = lane & 15;

    // ---- stage A (RT rows) and B (CT rows), 4-bit XOR swizzle ----
    {
        const int r0 = tid >> 4, c = tid & 15;
#pragma unroll
        for (int it = 0; it < 8; ++it) {
            int row = it * 16 + r0;
            int swz = ((c ^ (row & 15)) << 4);
            int4 va = *(const int4*)(featsN + (size_t)(RT * 128 + row) * DIM + c * 8);
            *(int4*)(Al + row * 256 + swz) = va;
            int4 vb = *(const int4*)(featsN + (size_t)(CT * 128 + row) * DIM + c * 8);
            *(int4*)(Bl + row * 256 + swz) = vb;
        }
    }
    __syncthreads();

    // ---- MFMA: 64 per wave (4m x 4n x 4k) ----
    f32x4 acc[4][4];
#pragma unroll
    for (int m = 0; m < 4; ++m)
#pragma unroll
        for (int n = 0; n < 4; ++n) acc[m][n] = (f32x4){0.f, 0.f, 0.f, 0.f};
#pragma unroll
    for (int kk = 0; kk < 4; ++kk) {
        bf16x8 af[4], bfr[4];
#pragma unroll
        for (int m = 0; m < 4; ++m) {
            int row = wr * 64 + m * 16 + l15;
            af[m] = __builtin_bit_cast(bf16x8,
                *(const int4*)(Al + row * 256 + (((kk * 4 + lg) ^ (row & 15)) << 4)));
        }
#pragma unroll
        for (int n = 0; n < 4; ++n) {
            int row = wc * 64 + n * 16 + l15;
            bfr[n] = __builtin_bit_cast(bf16x8,
                *(const int4*)(Bl + row * 256 + (((kk * 4 + lg) ^ (row & 15)) << 4)));
        }
#pragma unroll
        for (int m = 0; m < 4; ++m)
#pragma unroll
            for (int n = 0; n < 4; ++n)
                acc[m][n] = __builtin_amdgcn_mfma_f32_16x16x32_bf16(
                    af[m], bfr[n], acc[m][n], 0, 0, 0);
    }

    // ---- epilogue: u-form, DIRECT (P, N) accumulation ----
    const int rowbase = RT * 128 + wr * 64;
    const int colbase = CT * 128 + wc * 64;
    const float S2 = 46.166241308446828f;   // 32*log2(e)
    const float C2 = -23.083120654223414f;  // -0.5*S2

    int lc[4], lr[4][4];
#pragma unroll
    for (int n = 0; n < 4; ++n) lc[n] = labels[colbase + n * 16 + l15];
#pragma unroll
    for (int m = 0; m < 4; ++m)
#pragma unroll
        for (int r = 0; r < 4; ++r) lr[m][r] = labels[rowbase + m * 16 + lg * 4 + r];

    float rN[4][4], rP[4][4];
    float cN[4] = {0.f, 0.f, 0.f, 0.f}, cP[4] = {0.f, 0.f, 0.f, 0.f};

    if (diag) {
#pragma unroll
        for (int m = 0; m < 4; ++m) {
#pragma unroll
            for (int r = 0; r < 4; ++r) {
                const int grow = rowbase + m * 16 + lg * 4 + r;
                const int lrow = lr[m][r];
                float psum = 0.f, nsum = 0.f;
#pragma unroll
                for (int n = 0; n < 4; ++n) {
                    float sim = acc[m][n][r];
                    bool same = (lrow == lc[n]);
                    float u = same ? (1.25f - sim) : (sim + 0.25f);
                    float e2 = fmaxf(u, 0.f) * fmaf(S2, u, C2);
                    float v = EXP2F(e2);
                    bool self = (grow == colbase + n * 16 + l15);
                    float pv = (same && !self) ? v : 0.f;
                    float nv = same ? 0.f : v;   // self is same -> excluded
                    psum += pv; nsum += nv;
                }
                rP[m][r] = psum; rN[m][r] = nsum;
            }
        }
    } else {
#pragma unroll
        for (int m = 0; m < 4; ++m) {
#pragma unroll
            for (int r = 0; r < 4; ++r) {
                const int lrow = lr[m][r];
                float psum = 0.f, nsum = 0.f;
#pragma unroll
                for (int n = 0; n < 4; ++n) {
                    float sim = acc[m][n][r];
                    bool same = (lrow == lc[n]);
                    float u = same ? (1.25f - sim) : (sim + 0.25f);
                    float e2 = fmaxf(u, 0.f) * fmaf(S2, u, C2);
                    float v = EXP2F(e2);
                    float pv = same ? v : 0.f;
                    float nv = v - pv;            // exact: pv is v or 0
                    psum += pv; nsum += nv;
                    cP[n] += pv; cN[n] += nv;
                }
                rP[m][r] = psum; rN[m][r] = nsum;
            }
        }
    }

    // ---- col partials (off-diag only): shuffle reduce over lane groups ----
    if (!diag) {
#pragma unroll
        for (int n = 0; n < 4; ++n) {
            float p = cP[n], n_ = cN[n];
            p += __shfl_xor(p, 16); p += __shfl_xor(p, 32);
            n_ += __shfl_xor(n_, 16); n_ += __shfl_xor(n_, 32);
            if (lg == 0) {
                int gcol = colbase + n * 16 + l15;
                partial[(size_t)(RT * 2 + wr) * B + gcol] = packPN(p, n_);
            }
        }
    }

    // ---- row partials: LDS transpose reduce (aliased over dead tiles) ----
    __syncthreads();   // all LDS tile reads (MFMA fragments) complete
    {
        float2* T = tbuf + wv * 64 * 17;
#pragma unroll
        for (int m = 0; m < 4; ++m)
#pragma unroll
            for (int r = 0; r < 4; ++r)
                T[(m * 16 + lg * 4 + r) * 17 + l15] =
                    make_float2(rP[m][r], rN[m][r]);
    }
    __syncthreads();
    {
        const float2* T = tbuf + wv * 64 * 17 + lane * 17;
        float p = 0.f, n_ = 0.f;
#pragma unroll
        for (int c = 0; c < 16; ++c) {
            float2 t = T[c];
            p += t.x; n_ += t.y;
        }
        int grow = RT * 128 + wr * 64 + lane;
        partial[(size_t)(CT * 2 + wc) * B + grow] = packPN(p, n_);
    }
}

// ---------------- Kernel 3: per-row log1p(p*n), block sums ----------------
__global__ void rowloss_kernel(const unsigned int* __restrict__ partial,
                               double* __restrict__ blocksum, int B) {
    __shared__ double sdata[256];
    int tid = threadIdx.x;
    int row = blockIdx.x * 256 + tid;
    float p = 0.f, n = 0.f;
#pragma unroll
    for (int c = 0; c < 128; ++c) {
        unsigned int v = partial[(size_t)c * B + row];
        p += __uint_as_float(v << 16);
        n += __uint_as_float(v & 0xFFFF0000u);
    }
    sdata[tid] = log1p((double)p * (double)n);
    __syncthreads();
    for (int s = 128; s; s >>= 1) {
        if (tid < s) sdata[tid] += sdata[tid + s];
        __syncthreads();
    }
    if (tid == 0) blocksum[blockIdx.x] = sdata[0];
}

__global__ void final_kernel(const double* __restrict__ blocksum,
                             float* __restrict__ out, int nblk, int B) {
    __shared__ double sdata[64];
    int tid = threadIdx.x;
    sdata[tid] = (tid < nblk) ? blocksum[tid] : 0.0;
    __syncthreads();
    for (int s = 32; s; s >>= 1) {
        if (tid < s) sdata[tid] += sdata[tid + s];
        __syncthreads();
    }
    if (tid == 0) out[0] = (float)(sdata[0] / (double)B);
}

extern "C" void kernel_launch(void* const* d_in, const int* in_sizes, int n_in,
                              void* d_out, int out_size, void* d_ws, size_t ws_size,
                              hipStream_t stream) {
    const float* feats = (const float*)d_in[0];
    const int* labels = (const int*)d_in[1];
    float* out = (float*)d_out;
    int B = in_sizes[1];  // 8192

    // ws: featsN bf16 [B][128] (2MB) | partial u32 [128][B] (4MB) | blocksum (256B)
    unsigned int* featsN = (unsigned int*)d_ws;
    size_t off1 = ((size_t)B * DIM * 2 + 255) & ~(size_t)255;
    unsigned int* partial = (unsigned int*)((char*)d_ws + off1);
    size_t off2 = off1 + (((size_t)B * 128 * sizeof(unsigned int) + 255) & ~(size_t)255);
    double* blocksum = (double*)((char*)d_ws + off2);

    prep_kernel<<<B / 4, 256, 0, stream>>>(feats, featsN, B);

    int ntiles = B / 128;                      // 64
    int nblocks = ntiles * (ntiles + 1) / 2;   // 2080
    circle_main_kernel<<<nblocks, 256, 0, stream>>>((const unsigned short*)featsN,
                                                    labels, partial, B);

    int nblk = B / 256;                        // 32
    rowloss_kernel<<<nblk, 256, 0, stream>>>(partial, blocksum, B);
    final_kernel<<<1, 64, 0, stream>>>(blocksum, out, nblk, B);
}